// Round 8
// baseline (329.542 us; speedup 1.0000x reference)
//
#include <hip/hip_runtime.h>
#include <hip/hip_bf16.h>
#include <math.h>

#define TS 2048   // sequence length T
#define KD 1024   // model dim K
#define NH 16     // heads
#define SD 64     // head dim
#define MB 4096   // B*T rows
#define LOG2E 1.4426950408889634f

typedef __attribute__((ext_vector_type(8))) short bf16x8;   // 8 bf16 (4 VGPRs)
typedef __attribute__((ext_vector_type(4))) short bf16x4;   // 4 bf16 (2 VGPRs)
typedef __attribute__((ext_vector_type(4))) float f32x4;    // MFMA accumulator
typedef unsigned short ushort_t;

#define MFMA32(a, b, c) __builtin_amdgcn_mfma_f32_16x16x32_bf16(a, b, c, 0, 0, 0)

union frag8 { bf16x8 v8; bf16x4 h[2]; };

__device__ __forceinline__ ushort_t f2bf_rn(float f) {
    union { __hip_bfloat16 h; ushort_t u; } c;
    c.h = __float2bfloat16(f);
    return c.u;
}
__device__ __forceinline__ float bf2f(ushort_t u) {
    union { unsigned u; float f; } v; v.u = ((unsigned)u) << 16;
    return v.f;
}
__device__ __forceinline__ ushort4 pk4_bf(float a, float b, float c, float d) {
    union { __hip_bfloat162 h; ushort2 u; } x, y;
    x.h = __float22bfloat162_rn(make_float2(a, b));
    y.h = __float22bfloat162_rn(make_float2(c, d));
    return make_ushort4(x.u.x, x.u.y, y.u.x, y.u.y);
}
// async global -> LDS, 16 B per lane; lds ptr must be wave-uniform
__device__ __forceinline__ void gload_lds16(const void* g, void* l) {
    __builtin_amdgcn_global_load_lds(
        (const __attribute__((address_space(1))) unsigned int*)g,
        (__attribute__((address_space(3))) unsigned int*)l, 16, 0, 0);
}

// ---------------------------------------------------------------------------
// conv_all: z=0: x -> XH,XL (hi/lo); z=1: Wq*log2e -> hi/lo (folds exp->exp2);
// z=2: Wk -> hi/lo; z=3: Wv -> hi; z=4: Wu -> hi.
// ---------------------------------------------------------------------------
__global__ __launch_bounds__(256)
void conv_all(const float* __restrict__ x, const float* __restrict__ wq,
              const float* __restrict__ wk, const float* __restrict__ wv,
              const float* __restrict__ wu,
              ushort_t* XH, ushort_t* XL, ushort_t* WqH, ushort_t* WqL,
              ushort_t* WkH, ushort_t* WkL, ushort_t* WvH, ushort_t* WuH)
{
    int z = blockIdx.y;
    const float* src; ushort_t* H; ushort_t* L = nullptr; int nblk;
    switch (z) {
        case 0:  src = x;  H = XH;  L = XL;  nblk = 4096; break;
        case 1:  src = wq; H = WqH; L = WqL; nblk = 1024; break;
        case 2:  src = wk; H = WkH; L = WkL; nblk = 1024; break;
        case 3:  src = wv; H = WvH;          nblk = 1024; break;
        default: src = wu; H = WuH;          nblk = 1024; break;
    }
    if ((int)blockIdx.x >= nblk) return;
    int idx = blockIdx.x * 256 + threadIdx.x;      // float4 index
    float4 v = ((const float4*)src)[idx];
    if (z == 1) { v.x *= LOG2E; v.y *= LOG2E; v.z *= LOG2E; v.w *= LOG2E; }
    ushort_t h0 = f2bf_rn(v.x), h1 = f2bf_rn(v.y);
    ushort_t h2 = f2bf_rn(v.z), h3 = f2bf_rn(v.w);
    ((ushort4*)H)[idx] = make_ushort4(h0, h1, h2, h3);
    if (L) {
        ushort_t l0 = f2bf_rn(v.x - bf2f(h0)), l1 = f2bf_rn(v.y - bf2f(h1));
        ushort_t l2 = f2bf_rn(v.z - bf2f(h2)), l3 = f2bf_rn(v.w - bf2f(h3));
        ((ushort4*)L)[idx] = make_ushort4(l0, l1, l2, l3);
    }
}

// ---------------------------------------------------------------------------
// MFMA GEMM: C = A @ W^T. 64x128 tile, BK=32, 4 waves (2x2), 32x64/wave.
// (unchanged — known good)
// ---------------------------------------------------------------------------
__global__ __launch_bounds__(256)
void gemm_bf16(const ushort_t* __restrict__ Ah, const ushort_t* __restrict__ Al,
               const ushort_t* __restrict__ Bqh, const ushort_t* __restrict__ Bql,
               const ushort_t* __restrict__ Bkh, const ushort_t* __restrict__ Bkl,
               const ushort_t* __restrict__ Bvh, const ushort_t* __restrict__ Buh,
               ushort_t* __restrict__ OQh, ushort_t* __restrict__ OQl,
               ushort_t* __restrict__ OKh, ushort_t* __restrict__ OKl,
               ushort_t* __restrict__ OVt, float* __restrict__ OF,
               const float* __restrict__ bias, int epi_base)
{
    const int epi = epi_base + blockIdx.z;
    const ushort_t* Bh; const ushort_t* Bl = nullptr;
    if      (epi == 0) { Bh = Bqh; Bl = Bql; }
    else if (epi == 1) { Bh = Bkh; Bl = Bkl; }
    else if (epi == 2) { Bh = Bvh; }
    else               { Bh = Buh; }
    const bool terms3 = (epi < 2);

    __shared__ ushort_t sAh[64 * 32];    // 4 KB
    __shared__ ushort_t sAl[64 * 32];
    __shared__ ushort_t sBh[128 * 32];   // 8 KB
    __shared__ ushort_t sBl[128 * 32];

    const int tid = threadIdx.x;
    const int wave = tid >> 6, lane = tid & 63;
    const int col = lane & 15, quad = lane >> 4;
    const int wm = wave >> 1, wn = wave & 1;
    const int m0 = blockIdx.y * 64, n0 = blockIdx.x * 128;

    f32x4 acc[2][4];
#pragma unroll
    for (int i = 0; i < 2; ++i)
#pragma unroll
        for (int j = 0; j < 4; ++j) acc[i][j] = (f32x4){0.f, 0.f, 0.f, 0.f};

    for (int k0 = 0; k0 < KD; k0 += 32) {
        {   // A tile: 256 16B-slots, one per thread
            int row = tid >> 2, k8 = tid & 3;
            int lo  = wave * 64 * 8;                  // wave-uniform ushort offset
            gload_lds16(Ah + (size_t)(m0 + row) * KD + k0 + k8 * 8, sAh + lo);
            if (terms3)
                gload_lds16(Al + (size_t)(m0 + row) * KD + k0 + k8 * 8, sAl + lo);
        }
#pragma unroll
        for (int j = 0; j < 2; ++j) {   // B tile: 512 slots
            int s   = wave * 128 + j * 64 + lane;
            int row = s >> 2, k8 = s & 3;
            int lo  = (wave * 128 + j * 64) * 8;
            gload_lds16(Bh + (size_t)(n0 + row) * KD + k0 + k8 * 8, sBh + lo);
            if (terms3)
                gload_lds16(Bl + (size_t)(n0 + row) * KD + k0 + k8 * 8, sBl + lo);
        }
        __syncthreads();

        bf16x8 fbh[4], fbl[4];
#pragma unroll
        for (int j = 0; j < 4; ++j) {
            int r = (wn * 64 + j * 16 + col) * 32 + quad * 8;
            fbh[j] = *(const bf16x8*)&sBh[r];
            if (terms3) fbl[j] = *(const bf16x8*)&sBl[r];
        }
#pragma unroll
        for (int i = 0; i < 2; ++i) {
            int r = (wm * 32 + i * 16 + col) * 32 + quad * 8;
            bf16x8 fah = *(const bf16x8*)&sAh[r];
            if (terms3) {
                bf16x8 fal = *(const bf16x8*)&sAl[r];
#pragma unroll
                for (int j = 0; j < 4; ++j) {
                    acc[i][j] = MFMA32(fah, fbh[j], acc[i][j]);
                    acc[i][j] = MFMA32(fah, fbl[j], acc[i][j]);
                    acc[i][j] = MFMA32(fal, fbh[j], acc[i][j]);
                }
            } else {
#pragma unroll
                for (int j = 0; j < 4; ++j)
                    acc[i][j] = MFMA32(fah, fbh[j], acc[i][j]);
            }
        }
        __syncthreads();
    }

    // ---- epilogues (C/D: row m = quad*4+reg, col n = lane&15) ----
    if (epi <= 1) {
        ushort_t* OH = (epi == 0) ? OQh : OKh;
        ushort_t* OL = (epi == 0) ? OQl : OKl;
#pragma unroll
        for (int i = 0; i < 2; ++i) {
            int m = m0 + wm * 32 + i * 16 + quad * 4;
#pragma unroll
            for (int j = 0; j < 4; ++j) {
                int n = n0 + wn * 64 + j * 16 + col;
#pragma unroll
                for (int r = 0; r < 4; ++r) {
                    float v = acc[i][j][r];
                    ushort_t hv = f2bf_rn(v);
                    size_t off = (size_t)(m + r) * KD + n;
                    OH[off] = hv;
                    OL[off] = f2bf_rn(v - bf2f(hv));
                }
            }
        }
    } else if (epi == 2) {
#pragma unroll
        for (int i = 0; i < 2; ++i) {
            int m = m0 + wm * 32 + i * 16 + quad * 4;
            int bb = m >> 11, t = m & (TS - 1);
#pragma unroll
            for (int j = 0; j < 4; ++j) {
                int n = n0 + wn * 64 + j * 16 + col;
                int hh = n >> 6, d = n & 63;
                ushort4 pk = pk4_bf(acc[i][j][0], acc[i][j][1], acc[i][j][2], acc[i][j][3]);
                *(ushort4*)(OVt + ((size_t)(bb * NH + hh) * SD + d) * TS + t) = pk;
            }
        }
    } else {
#pragma unroll
        for (int i = 0; i < 2; ++i) {
            int m = m0 + wm * 32 + i * 16 + quad * 4;
#pragma unroll
            for (int j = 0; j < 4; ++j) {
                int n = n0 + wn * 64 + j * 16 + col;
                float bj = bias[n];
#pragma unroll
                for (int r = 0; r < 4; ++r)
                    OF[(size_t)(m + r) * KD + n] = acc[i][j][r] + bj;
            }
        }
    }
}

// ---------------------------------------------------------------------------
// MFMA flash attention, barrier-free + EXPLICIT register double-buffer.
// Keys distributed across waves (wave w owns keys [kt*64+w*16,+16), all 64 q).
// Ping-pong tile buffers: loads for tile kt+1 are issued BEFORE computing
// tile kt, so the waitcnt before compute-kt leaves the next tile's 9 loads
// in flight behind ~800 cyc of MFMA/exp work (round-7 failure: compiler
// would not pipeline on its own; every kt exposed a full memory round trip).
// ---------------------------------------------------------------------------
#define LOADTILE(t)                                                         \
    do {                                                                    \
        (t).kh0 = *(const bf16x8*)(kh_p);                                   \
        (t).kh1 = *(const bf16x8*)(kh_p + 32);                              \
        (t).kl0 = *(const bf16x8*)(kl_p);                                   \
        (t).kl1 = *(const bf16x8*)(kl_p + 32);                              \
        (t).av[0].h[0] = *(const bf16x4*)(vt_p);                            \
        (t).av[1].h[0] = *(const bf16x4*)(vt_p + 16 * TS);                  \
        (t).av[2].h[0] = *(const bf16x4*)(vt_p + 32 * TS);                  \
        (t).av[3].h[0] = *(const bf16x4*)(vt_p + 48 * TS);                  \
        (t).mv = *(const int4*)mp;                                          \
        kh_p += 64 * KD; kl_p += 64 * KD; vt_p += 64; mp += 64;             \
    } while (0)

#define COMPUTETILE(t)                                                      \
    do {                                                                    \
        f32x4 sinit;                                                        \
        sinit[0] = (t).mv.x ? 0.f : -INFINITY;                              \
        sinit[1] = (t).mv.y ? 0.f : -INFINITY;                              \
        sinit[2] = (t).mv.z ? 0.f : -INFINITY;                              \
        sinit[3] = (t).mv.w ? 0.f : -INFINITY;                              \
        _Pragma("unroll")                                                   \
        for (int qf = 0; qf < 4; ++qf) {                                    \
            f32x4 s1 = sinit;                                               \
            f32x4 s2 = (f32x4){0.f, 0.f, 0.f, 0.f};                         \
            s1 = MFMA32((t).kh0, bqh[qf][0], s1);                           \
            s2 = MFMA32((t).kl0, bqh[qf][0], s2);                           \
            s2 = MFMA32((t).kh0, bql[qf][0], s2);                           \
            s1 = MFMA32((t).kh1, bqh[qf][1], s1);                           \
            s2 = MFMA32((t).kl1, bqh[qf][1], s2);                           \
            s2 = MFMA32((t).kh1, bql[qf][1], s2);                           \
            float p0 = exp2f(s1[0] + s2[0]);                                \
            float p1 = exp2f(s1[1] + s2[1]);                                \
            float p2 = exp2f(s1[2] + s2[2]);                                \
            float p3 = exp2f(s1[3] + s2[3]);                                \
            lp[qf] += (p0 + p1) + (p2 + p3);                                \
            union { ushort4 u4; bf16x4 v4; } pk;                            \
            pk.u4 = pk4_bf(p0, p1, p2, p3);                                 \
            bp4[qf].h[0] = pk.v4;                                           \
        }                                                                   \
        _Pragma("unroll")                                                   \
        for (int dt = 0; dt < 4; ++dt) {                                    \
            _Pragma("unroll")                                               \
            for (int qf = 0; qf < 4; ++qf)                                  \
                O[dt][qf] = MFMA32((t).av[dt].v8, bp4[qf].v8, O[dt][qf]);   \
        }                                                                   \
    } while (0)

struct KVTile {
    bf16x8 kh0, kh1, kl0, kl1;
    frag8  av[4];
    int4   mv;
};

__global__ __launch_bounds__(256, 2)
void attn_mfma(const ushort_t* __restrict__ QH, const ushort_t* __restrict__ QL,
               const ushort_t* __restrict__ KH, const ushort_t* __restrict__ KL,
               const ushort_t* __restrict__ VT, const int* __restrict__ mask,
               ushort_t* __restrict__ YH)
{
    const int qt = blockIdx.x;       // 0..31
    const int h  = blockIdx.y;
    const int b  = blockIdx.z;
    const int bh = b * NH + h;

    const int tid  = threadIdx.x;
    const int wave = tid >> 6;
    const int lane = tid & 63;
    const int col  = lane & 15;
    const int quad = lane >> 4;

    __shared__ float Of[4096];       // 16 KB, end-phase O reduce only
    __shared__ float lred[4][64];    // 1 KB

    // ---- Q fragments, held in registers for the whole kernel ----
    bf16x8 bqh[4][2], bql[4][2];
#pragma unroll
    for (int qf = 0; qf < 4; ++qf) {
        size_t qrow = (size_t)(b * TS + qt * 64 + qf * 16 + col) * KD + h * SD;
#pragma unroll
        for (int c = 0; c < 2; ++c) {
            bqh[qf][c] = *(const bf16x8*)(QH + qrow + c * 32 + quad * 8);
            bql[qf][c] = *(const bf16x8*)(QL + qrow + c * 32 + quad * 8);
        }
    }

    // ---- per-wave direct-global pointers (bumped inside LOADTILE) ----
    const ushort_t* kh_p = KH + (size_t)(b * TS + wave * 16 + col) * KD + h * SD + quad * 8;
    const ushort_t* kl_p = KL + (size_t)(b * TS + wave * 16 + col) * KD + h * SD + quad * 8;
    const ushort_t* vt_p = VT + ((size_t)bh * SD + col) * TS + wave * 16 + quad * 4;
    const int*      mp   = mask + b * TS + wave * 16 + quad * 4;

    float lp[4] = {0.f, 0.f, 0.f, 0.f};
    f32x4 O[4][4];                        // [dt][qf], O^T: row=d, col=q
#pragma unroll
    for (int dt = 0; dt < 4; ++dt)
#pragma unroll
        for (int qf = 0; qf < 4; ++qf) O[dt][qf] = (f32x4){0.f, 0.f, 0.f, 0.f};

    frag8 bp4[4];
    KVTile ta, tb;
#pragma unroll
    for (int i = 0; i < 4; ++i) {
        bp4[i].v8   = (bf16x8){0, 0, 0, 0, 0, 0, 0, 0};
        ta.av[i].v8 = (bf16x8){0, 0, 0, 0, 0, 0, 0, 0};   // persistent zero k-pad
        tb.av[i].v8 = (bf16x8){0, 0, 0, 0, 0, 0, 0, 0};
    }

    // ---- software-pipelined main loop (depth-1 prefetch, ping-pong) ----
    LOADTILE(ta);                                  // kt = 0
    for (int kt = 0; kt < TS / 64; kt += 2) {
        LOADTILE(tb);                              // kt+1 in flight
        COMPUTETILE(ta);                           // waits only on ta's loads
        if (kt + 2 < TS / 64) LOADTILE(ta);        // kt+2 in flight
        COMPUTETILE(tb);
    }

    // ---- l: reduce over quads, publish per wave ----
#pragma unroll
    for (int qf = 0; qf < 4; ++qf) {
        float v = lp[qf];
        v += __shfl_xor(v, 16);
        v += __shfl_xor(v, 32);
        if (lane < 16) lred[wave][qf * 16 + lane] = v;
    }

    // ---- staged O-reduce through 16 KB of LDS (3 rounds) ----
#pragma unroll
    for (int w = 1; w < 4; ++w) {
        __syncthreads();
        if (wave == w) {
#pragma unroll
            for (int dt = 0; dt < 4; ++dt)
#pragma unroll
                for (int qf = 0; qf < 4; ++qf)
                    *(f32x4*)&Of[((dt * 4 + qf) * 64 + lane) * 4] = O[dt][qf];
        }
        __syncthreads();
        if (wave == 0) {
#pragma unroll
            for (int dt = 0; dt < 4; ++dt)
#pragma unroll
                for (int qf = 0; qf < 4; ++qf)
                    O[dt][qf] += *(const f32x4*)&Of[((dt * 4 + qf) * 64 + lane) * 4];
        }
    }
    if (wave == 0) {
        float linv[4];
#pragma unroll
        for (int qf = 0; qf < 4; ++qf) {
            int q = qf * 16 + col;
            linv[qf] = 1.f / (lred[0][q] + lred[1][q] + lred[2][q] + lred[3][q]);
        }
#pragma unroll
        for (int dt = 0; dt < 4; ++dt)
#pragma unroll
            for (int qf = 0; qf < 4; ++qf) {
                ushort4 pk = pk4_bf(O[dt][qf][0] * linv[qf], O[dt][qf][1] * linv[qf],
                                    O[dt][qf][2] * linv[qf], O[dt][qf][3] * linv[qf]);
                *(ushort4*)(YH + (size_t)(b * TS + qt * 64 + qf * 16 + col) * KD +
                            h * SD + dt * 16 + quad * 4) = pk;
            }
    }
}

// ---------------------------------------------------------------------------
extern "C" void kernel_launch(void* const* d_in, const int* in_sizes, int n_in,
                              void* d_out, int out_size, void* d_ws, size_t ws_size,
                              hipStream_t stream) {
    const float* x    = (const float*)d_in[0];
    const int*   mask = (const int*)d_in[1];
    const float* Wk   = (const float*)d_in[2];
    const float* Wq   = (const float*)d_in[3];
    const float* Wv   = (const float*)d_in[4];
    const float* Wu   = (const float*)d_in[5];
    const float* bu   = (const float*)d_in[6];
    float* out = (float*)d_out;

    char* w = (char*)d_ws;
    const size_t M1 = (size_t)1 << 20;
    // workspace plan (60 MB peak; VT lives in d_out until the U gemm):
    ushort_t* XH  = (ushort_t*)(w);              // [0,8M)
    ushort_t* XL  = (ushort_t*)(w + 8  * M1);    // [8,16M)
    ushort_t* WqH = (ushort_t*)(w + 16 * M1);
    ushort_t* WqL = (ushort_t*)(w + 18 * M1);
    ushort_t* WkH = (ushort_t*)(w + 20 * M1);
    ushort_t* WkL = (ushort_t*)(w + 22 * M1);
    ushort_t* WvH = (ushort_t*)(w + 24 * M1);    // [24,26M)
    ushort_t* QHb = (ushort_t*)(w + 26 * M1);    // [26,34M)
    ushort_t* QLb = (ushort_t*)(w + 34 * M1);
    ushort_t* KHb = (ushort_t*)(w + 42 * M1);
    ushort_t* KLb = (ushort_t*)(w + 50 * M1);    // ..58M
    ushort_t* WuH = (ushort_t*)(w + 58 * M1);    // [58,60M)
    ushort_t* VTb = (ushort_t*)d_out;            // 8 MB scratch in d_out
    ushort_t* YHb = (ushort_t*)(w);              // over XH (dead after QKV)

    dim3 blk(256);
    conv_all<<<dim3(4096, 5), blk, 0, stream>>>(x, Wq, Wk, Wv, Wu,
                                                XH, XL, WqH, WqL, WkH, WkL, WvH, WuH);
    // fused Q,K,V projections: 1536 blocks = 6/CU
    gemm_bf16<<<dim3(8, 64, 3), blk, 0, stream>>>(XH, XL, WqH, WqL, WkH, WkL, WvH, WuH,
                                                  QHb, QLb, KHb, KLb, VTb, nullptr,
                                                  nullptr, 0);
    attn_mfma<<<dim3(32, NH, 2), blk, 0, stream>>>(QHb, QLb, KHb, KLb, VTb, mask, YHb);
    // output projection + bias: 512 blocks = 2/CU
    gemm_bf16<<<dim3(8, 64, 1), blk, 0, stream>>>(YHb, nullptr, WqH, WqL, WkH, WkL, WvH, WuH,
                                                  nullptr, nullptr, nullptr, nullptr, nullptr,
                                                  out, bu, 3);
}

// Round 9
// 300.143 us; speedup vs baseline: 1.0980x; 1.0980x over previous
//
#include <hip/hip_runtime.h>
#include <hip/hip_bf16.h>
#include <math.h>

#define TS 2048   // sequence length T
#define KD 1024   // model dim K
#define NH 16     // heads
#define SD 64     // head dim
#define MB 4096   // B*T rows
#define LOG2E 1.4426950408889634f

typedef __attribute__((ext_vector_type(8))) short bf16x8;   // 8 bf16 (4 VGPRs)
typedef __attribute__((ext_vector_type(4))) short bf16x4;   // 4 bf16 (2 VGPRs)
typedef __attribute__((ext_vector_type(4))) float f32x4;    // MFMA accumulator
typedef unsigned short ushort_t;

#define MFMA32(a, b, c) __builtin_amdgcn_mfma_f32_16x16x32_bf16(a, b, c, 0, 0, 0)

union frag8 { bf16x8 v8; bf16x4 h[2]; };

__device__ __forceinline__ ushort_t f2bf_rn(float f) {
    union { __hip_bfloat16 h; ushort_t u; } c;
    c.h = __float2bfloat16(f);
    return c.u;
}
__device__ __forceinline__ float bf2f(ushort_t u) {
    union { unsigned u; float f; } v; v.u = ((unsigned)u) << 16;
    return v.f;
}
__device__ __forceinline__ ushort4 pk4_bf(float a, float b, float c, float d) {
    union { __hip_bfloat162 h; ushort2 u; } x, y;
    x.h = __float22bfloat162_rn(make_float2(a, b));
    y.h = __float22bfloat162_rn(make_float2(c, d));
    return make_ushort4(x.u.x, x.u.y, y.u.x, y.u.y);
}
// async global -> LDS, 16 B per lane; lds ptr must be wave-uniform
__device__ __forceinline__ void gload_lds16(const void* g, void* l) {
    __builtin_amdgcn_global_load_lds(
        (const __attribute__((address_space(1))) unsigned int*)g,
        (__attribute__((address_space(3))) unsigned int*)l, 16, 0, 0);
}

// ---------------------------------------------------------------------------
// conv_all: z=0: x -> XH,XL (hi/lo); z=1: Wq*log2e -> hi/lo (folds exp->exp2);
// z=2: Wk -> hi/lo; z=3: Wv -> hi; z=4: Wu -> hi.
// ---------------------------------------------------------------------------
__global__ __launch_bounds__(256)
void conv_all(const float* __restrict__ x, const float* __restrict__ wq,
              const float* __restrict__ wk, const float* __restrict__ wv,
              const float* __restrict__ wu,
              ushort_t* XH, ushort_t* XL, ushort_t* WqH, ushort_t* WqL,
              ushort_t* WkH, ushort_t* WkL, ushort_t* WvH, ushort_t* WuH)
{
    int z = blockIdx.y;
    const float* src; ushort_t* H; ushort_t* L = nullptr; int nblk;
    switch (z) {
        case 0:  src = x;  H = XH;  L = XL;  nblk = 4096; break;
        case 1:  src = wq; H = WqH; L = WqL; nblk = 1024; break;
        case 2:  src = wk; H = WkH; L = WkL; nblk = 1024; break;
        case 3:  src = wv; H = WvH;          nblk = 1024; break;
        default: src = wu; H = WuH;          nblk = 1024; break;
    }
    if ((int)blockIdx.x >= nblk) return;
    int idx = blockIdx.x * 256 + threadIdx.x;      // float4 index
    float4 v = ((const float4*)src)[idx];
    if (z == 1) { v.x *= LOG2E; v.y *= LOG2E; v.z *= LOG2E; v.w *= LOG2E; }
    ushort_t h0 = f2bf_rn(v.x), h1 = f2bf_rn(v.y);
    ushort_t h2 = f2bf_rn(v.z), h3 = f2bf_rn(v.w);
    ((ushort4*)H)[idx] = make_ushort4(h0, h1, h2, h3);
    if (L) {
        ushort_t l0 = f2bf_rn(v.x - bf2f(h0)), l1 = f2bf_rn(v.y - bf2f(h1));
        ushort_t l2 = f2bf_rn(v.z - bf2f(h2)), l3 = f2bf_rn(v.w - bf2f(h3));
        ((ushort4*)L)[idx] = make_ushort4(l0, l1, l2, l3);
    }
}

// ---------------------------------------------------------------------------
// MFMA GEMM: C = A @ W^T. 64x128 tile, BK=32, 4 waves (2x2), 32x64/wave.
// (unchanged — known good)
// ---------------------------------------------------------------------------
__global__ __launch_bounds__(256)
void gemm_bf16(const ushort_t* __restrict__ Ah, const ushort_t* __restrict__ Al,
               const ushort_t* __restrict__ Bqh, const ushort_t* __restrict__ Bql,
               const ushort_t* __restrict__ Bkh, const ushort_t* __restrict__ Bkl,
               const ushort_t* __restrict__ Bvh, const ushort_t* __restrict__ Buh,
               ushort_t* __restrict__ OQh, ushort_t* __restrict__ OQl,
               ushort_t* __restrict__ OKh, ushort_t* __restrict__ OKl,
               ushort_t* __restrict__ OVt, float* __restrict__ OF,
               const float* __restrict__ bias, int epi_base)
{
    const int epi = epi_base + blockIdx.z;
    const ushort_t* Bh; const ushort_t* Bl = nullptr;
    if      (epi == 0) { Bh = Bqh; Bl = Bql; }
    else if (epi == 1) { Bh = Bkh; Bl = Bkl; }
    else if (epi == 2) { Bh = Bvh; }
    else               { Bh = Buh; }
    const bool terms3 = (epi < 2);

    __shared__ ushort_t sAh[64 * 32];    // 4 KB
    __shared__ ushort_t sAl[64 * 32];
    __shared__ ushort_t sBh[128 * 32];   // 8 KB
    __shared__ ushort_t sBl[128 * 32];

    const int tid = threadIdx.x;
    const int wave = tid >> 6, lane = tid & 63;
    const int col = lane & 15, quad = lane >> 4;
    const int wm = wave >> 1, wn = wave & 1;
    const int m0 = blockIdx.y * 64, n0 = blockIdx.x * 128;

    f32x4 acc[2][4];
#pragma unroll
    for (int i = 0; i < 2; ++i)
#pragma unroll
        for (int j = 0; j < 4; ++j) acc[i][j] = (f32x4){0.f, 0.f, 0.f, 0.f};

    for (int k0 = 0; k0 < KD; k0 += 32) {
        {   // A tile: 256 16B-slots, one per thread
            int row = tid >> 2, k8 = tid & 3;
            int lo  = wave * 64 * 8;                  // wave-uniform ushort offset
            gload_lds16(Ah + (size_t)(m0 + row) * KD + k0 + k8 * 8, sAh + lo);
            if (terms3)
                gload_lds16(Al + (size_t)(m0 + row) * KD + k0 + k8 * 8, sAl + lo);
        }
#pragma unroll
        for (int j = 0; j < 2; ++j) {   // B tile: 512 slots
            int s   = wave * 128 + j * 64 + lane;
            int row = s >> 2, k8 = s & 3;
            int lo  = (wave * 128 + j * 64) * 8;
            gload_lds16(Bh + (size_t)(n0 + row) * KD + k0 + k8 * 8, sBh + lo);
            if (terms3)
                gload_lds16(Bl + (size_t)(n0 + row) * KD + k0 + k8 * 8, sBl + lo);
        }
        __syncthreads();

        bf16x8 fbh[4], fbl[4];
#pragma unroll
        for (int j = 0; j < 4; ++j) {
            int r = (wn * 64 + j * 16 + col) * 32 + quad * 8;
            fbh[j] = *(const bf16x8*)&sBh[r];
            if (terms3) fbl[j] = *(const bf16x8*)&sBl[r];
        }
#pragma unroll
        for (int i = 0; i < 2; ++i) {
            int r = (wm * 32 + i * 16 + col) * 32 + quad * 8;
            bf16x8 fah = *(const bf16x8*)&sAh[r];
            if (terms3) {
                bf16x8 fal = *(const bf16x8*)&sAl[r];
#pragma unroll
                for (int j = 0; j < 4; ++j) {
                    acc[i][j] = MFMA32(fah, fbh[j], acc[i][j]);
                    acc[i][j] = MFMA32(fah, fbl[j], acc[i][j]);
                    acc[i][j] = MFMA32(fal, fbh[j], acc[i][j]);
                }
            } else {
#pragma unroll
                for (int j = 0; j < 4; ++j)
                    acc[i][j] = MFMA32(fah, fbh[j], acc[i][j]);
            }
        }
        __syncthreads();
    }

    // ---- epilogues (C/D: row m = quad*4+reg, col n = lane&15) ----
    if (epi <= 1) {
        ushort_t* OH = (epi == 0) ? OQh : OKh;
        ushort_t* OL = (epi == 0) ? OQl : OKl;
#pragma unroll
        for (int i = 0; i < 2; ++i) {
            int m = m0 + wm * 32 + i * 16 + quad * 4;
#pragma unroll
            for (int j = 0; j < 4; ++j) {
                int n = n0 + wn * 64 + j * 16 + col;
#pragma unroll
                for (int r = 0; r < 4; ++r) {
                    float v = acc[i][j][r];
                    ushort_t hv = f2bf_rn(v);
                    size_t off = (size_t)(m + r) * KD + n;
                    OH[off] = hv;
                    OL[off] = f2bf_rn(v - bf2f(hv));
                }
            }
        }
    } else if (epi == 2) {
#pragma unroll
        for (int i = 0; i < 2; ++i) {
            int m = m0 + wm * 32 + i * 16 + quad * 4;
            int bb = m >> 11, t = m & (TS - 1);
#pragma unroll
            for (int j = 0; j < 4; ++j) {
                int n = n0 + wn * 64 + j * 16 + col;
                int hh = n >> 6, d = n & 63;
                ushort4 pk = pk4_bf(acc[i][j][0], acc[i][j][1], acc[i][j][2], acc[i][j][3]);
                *(ushort4*)(OVt + ((size_t)(bb * NH + hh) * SD + d) * TS + t) = pk;
            }
        }
    } else {
#pragma unroll
        for (int i = 0; i < 2; ++i) {
            int m = m0 + wm * 32 + i * 16 + quad * 4;
#pragma unroll
            for (int j = 0; j < 4; ++j) {
                int n = n0 + wn * 64 + j * 16 + col;
                float bj = bias[n];
#pragma unroll
                for (int r = 0; r < 4; ++r)
                    OF[(size_t)(m + r) * KD + n] = acc[i][j][r] + bj;
            }
        }
    }
}

// ---------------------------------------------------------------------------
// MFMA flash attention — round-6 structure (best measured) + XCD-pinned grid.
// grid = (bh=32, qt=32): linear block id = qt*32 + bh -> XCD = bh % 8, so all
// 32 q-tile blocks of one (b,h) run on ONE XCD; per-XCD hot set = 4 heads x
// 768 KB = 3 MB < 4 MB L2 -> K/V re-reads become L2 hits instead of L3/HBM.
// Keys distributed across waves; K hi/lo + V^T staged per kt via swizzled
// global_load_lds; mask folded into S accumulator init; P in registers as
// zero-padded PV B-operand; cross-wave O/l reduce at the end.
// ---------------------------------------------------------------------------
__global__ __launch_bounds__(256, 2)
void attn_mfma(const ushort_t* __restrict__ QH, const ushort_t* __restrict__ QL,
               const ushort_t* __restrict__ KH, const ushort_t* __restrict__ KL,
               const ushort_t* __restrict__ VT, const int* __restrict__ mask,
               ushort_t* __restrict__ YH)
{
    const int bh = blockIdx.x;       // 0..31  (fastest dim -> pins XCD = bh%8)
    const int qt = blockIdx.y;       // 0..31
    const int h  = bh & (NH - 1);
    const int b  = bh >> 4;

    const int tid  = threadIdx.x;
    const int wave = tid >> 6;
    const int lane = tid & 63;
    const int col  = lane & 15;
    const int quad = lane >> 4;

    __shared__ ushort_t smem[12288];     // 24 KB: staging; reused for O-reduce
    ushort_t* sKH = smem;                // [key][d] swizzled, 8 KB
    ushort_t* sKL = smem + 4096;
    ushort_t* sVT = smem + 8192;         // [d][key] swizzled, 8 KB
    __shared__ float lred[4][64];

    // ---- Q fragments, held in registers for the whole kernel ----
    bf16x8 bqh[4][2], bql[4][2];
#pragma unroll
    for (int qf = 0; qf < 4; ++qf) {
        size_t qrow = (size_t)(b * TS + qt * 64 + qf * 16 + col) * KD + h * SD;
#pragma unroll
        for (int c = 0; c < 2; ++c) {
            bqh[qf][c] = *(const bf16x8*)(QH + qrow + c * 32 + quad * 8);
            bql[qf][c] = *(const bf16x8*)(QL + qrow + c * 32 + quad * 8);
        }
    }

    // ---- hoisted staging pointers: chunk r -> {r<2: KH, r<4: KL, else VT} ----
    const int l8 = lane >> 3, l7 = lane & 7;
    const ushort_t* gp[6];
    ushort_t* ld[6];
#pragma unroll
    for (int r = 0; r < 6; ++r) {
        int cc  = (r & 1) * 4 + wave;          // chunk within its matrix (0..7)
        int row = cc * 8 + l8;                 // 0..63
        int gs  = l7 ^ (row & 7);              // XOR swizzle
        if (r < 2)      gp[r] = KH + (size_t)(b * TS + row) * KD + h * SD + gs * 8;
        else if (r < 4) gp[r] = KL + (size_t)(b * TS + row) * KD + h * SD + gs * 8;
        else            gp[r] = VT + ((size_t)bh * SD + row) * TS + gs * 8;
        ld[r] = ((r < 2) ? sKH : (r < 4) ? sKL : sVT) + cc * 512;
    }
    const int* mp = mask + b * TS + wave * 16 + quad * 4;

    float lp[4] = {0.f, 0.f, 0.f, 0.f};
    f32x4 O[4][4];                        // [dt][qf], O^T: row=d, col=q
#pragma unroll
    for (int dt = 0; dt < 4; ++dt)
#pragma unroll
        for (int qf = 0; qf < 4; ++qf) O[dt][qf] = (f32x4){0.f, 0.f, 0.f, 0.f};

    frag8 av[4], bp4[4];
#pragma unroll
    for (int i = 0; i < 4; ++i) {
        av[i].v8  = (bf16x8){0, 0, 0, 0, 0, 0, 0, 0};
        bp4[i].v8 = (bf16x8){0, 0, 0, 0, 0, 0, 0, 0};
    }

    for (int kt = 0; kt < TS / 64; ++kt) {
#pragma unroll
        for (int r = 0; r < 6; ++r) gload_lds16(gp[r], ld[r]);
        int4 mv = *(const int4*)mp;
        mp += 64;
#pragma unroll
        for (int r = 0; r < 6; ++r) gp[r] += (r < 4) ? 64 * KD : 64;
        __syncthreads();

        // masked keys: S starts at -inf -> exp2 gives exactly 0
        f32x4 sinit;
        sinit[0] = mv.x ? 0.f : -INFINITY;
        sinit[1] = mv.y ? 0.f : -INFINITY;
        sinit[2] = mv.z ? 0.f : -INFINITY;
        sinit[3] = mv.w ? 0.f : -INFINITY;

        // ---- K / V fragments for this wave's 16-key strip ----
        bf16x8 akh[2], akl[2];
#pragma unroll
        for (int c = 0; c < 2; ++c) {
            int sl = (c * 4 + quad) ^ (col & 7);
            akh[c] = *(const bf16x8*)&sKH[((wave * 16 + col) * 8 + sl) * 8];
            akl[c] = *(const bf16x8*)&sKL[((wave * 16 + col) * 8 + sl) * 8];
        }
#pragma unroll
        for (int dt = 0; dt < 4; ++dt) {
            int sl = (wave * 2 + (quad >> 1)) ^ (col & 7);
            av[dt].h[0] = *(const bf16x4*)&sVT[((dt * 16 + col) * 8 + sl) * 8 + (quad & 1) * 4];
        }

        // ---- S^T strips (hi/lo 3-term, 2 indep chains) + exp2 + pack P ----
#pragma unroll
        for (int qf = 0; qf < 4; ++qf) {
            f32x4 s1 = sinit;
            f32x4 s2 = (f32x4){0.f, 0.f, 0.f, 0.f};
            s1 = MFMA32(akh[0], bqh[qf][0], s1);
            s2 = MFMA32(akl[0], bqh[qf][0], s2);
            s2 = MFMA32(akh[0], bql[qf][0], s2);
            s1 = MFMA32(akh[1], bqh[qf][1], s1);
            s2 = MFMA32(akl[1], bqh[qf][1], s2);
            s2 = MFMA32(akh[1], bql[qf][1], s2);
            float p0 = exp2f(s1[0] + s2[0]);
            float p1 = exp2f(s1[1] + s2[1]);
            float p2 = exp2f(s1[2] + s2[2]);
            float p3 = exp2f(s1[3] + s2[3]);
            lp[qf] += (p0 + p1) + (p2 + p3);
            union { ushort4 u4; bf16x4 v4; } pk;
            pk.u4 = pk4_bf(p0, p1, p2, p3);
            bp4[qf].h[0] = pk.v4;
        }

        // ---- O^T += V^T x P^T (zero-padded K=32 MFMA, P direct from regs) ----
#pragma unroll
        for (int dt = 0; dt < 4; ++dt)
#pragma unroll
            for (int qf = 0; qf < 4; ++qf)
                O[dt][qf] = MFMA32(av[dt].v8, bp4[qf].v8, O[dt][qf]);

        __syncthreads();
    }

    // ---- l: reduce over quads, publish per wave ----
#pragma unroll
    for (int qf = 0; qf < 4; ++qf) {
        float v = lp[qf];
        v += __shfl_xor(v, 16);
        v += __shfl_xor(v, 32);
        if (lane < 16) lred[wave][qf * 16 + lane] = v;
    }

    // ---- staged O-reduce through 16 KB of LDS (3 rounds) ----
    float* Of = (float*)smem;
#pragma unroll
    for (int w = 1; w < 4; ++w) {
        __syncthreads();
        if (wave == w) {
#pragma unroll
            for (int dt = 0; dt < 4; ++dt)
#pragma unroll
                for (int qf = 0; qf < 4; ++qf)
                    *(f32x4*)&Of[((dt * 4 + qf) * 64 + lane) * 4] = O[dt][qf];
        }
        __syncthreads();
        if (wave == 0) {
#pragma unroll
            for (int dt = 0; dt < 4; ++dt)
#pragma unroll
                for (int qf = 0; qf < 4; ++qf)
                    O[dt][qf] += *(const f32x4*)&Of[((dt * 4 + qf) * 64 + lane) * 4];
        }
    }
    if (wave == 0) {
        float linv[4];
#pragma unroll
        for (int qf = 0; qf < 4; ++qf) {
            int q = qf * 16 + col;
            linv[qf] = 1.f / (lred[0][q] + lred[1][q] + lred[2][q] + lred[3][q]);
        }
#pragma unroll
        for (int dt = 0; dt < 4; ++dt)
#pragma unroll
            for (int qf = 0; qf < 4; ++qf) {
                ushort4 pk = pk4_bf(O[dt][qf][0] * linv[qf], O[dt][qf][1] * linv[qf],
                                    O[dt][qf][2] * linv[qf], O[dt][qf][3] * linv[qf]);
                *(ushort4*)(YH + (size_t)(b * TS + qt * 64 + qf * 16 + col) * KD +
                            h * SD + dt * 16 + quad * 4) = pk;
            }
    }
}

// ---------------------------------------------------------------------------
extern "C" void kernel_launch(void* const* d_in, const int* in_sizes, int n_in,
                              void* d_out, int out_size, void* d_ws, size_t ws_size,
                              hipStream_t stream) {
    const float* x    = (const float*)d_in[0];
    const int*   mask = (const int*)d_in[1];
    const float* Wk   = (const float*)d_in[2];
    const float* Wq   = (const float*)d_in[3];
    const float* Wv   = (const float*)d_in[4];
    const float* Wu   = (const float*)d_in[5];
    const float* bu   = (const float*)d_in[6];
    float* out = (float*)d_out;

    char* w = (char*)d_ws;
    const size_t M1 = (size_t)1 << 20;
    // workspace plan (60 MB peak; VT lives in d_out until the U gemm):
    ushort_t* XH  = (ushort_t*)(w);              // [0,8M)
    ushort_t* XL  = (ushort_t*)(w + 8  * M1);    // [8,16M)
    ushort_t* WqH = (ushort_t*)(w + 16 * M1);
    ushort_t* WqL = (ushort_t*)(w + 18 * M1);
    ushort_t* WkH = (ushort_t*)(w + 20 * M1);
    ushort_t* WkL = (ushort_t*)(w + 22 * M1);
    ushort_t* WvH = (ushort_t*)(w + 24 * M1);    // [24,26M)
    ushort_t* QHb = (ushort_t*)(w + 26 * M1);    // [26,34M)
    ushort_t* QLb = (ushort_t*)(w + 34 * M1);
    ushort_t* KHb = (ushort_t*)(w + 42 * M1);
    ushort_t* KLb = (ushort_t*)(w + 50 * M1);    // ..58M
    ushort_t* WuH = (ushort_t*)(w + 58 * M1);    // [58,60M)
    ushort_t* VTb = (ushort_t*)d_out;            // 8 MB scratch in d_out
    ushort_t* YHb = (ushort_t*)(w);              // over XH (dead after QKV)

    dim3 blk(256);
    conv_all<<<dim3(4096, 5), blk, 0, stream>>>(x, Wq, Wk, Wv, Wu,
                                                XH, XL, WqH, WqL, WkH, WkL, WvH, WuH);
    // fused Q,K,V projections: 1536 blocks = 6/CU
    gemm_bf16<<<dim3(8, 64, 3), blk, 0, stream>>>(XH, XL, WqH, WqL, WkH, WkL, WvH, WuH,
                                                  QHb, QLb, KHb, KLb, VTb, nullptr,
                                                  nullptr, 0);
    // attention: grid(bh, qt) so each (b,h)'s 32 blocks share one XCD's L2
    attn_mfma<<<dim3(NH * 2, 32), blk, 0, stream>>>(QHb, QLb, KHb, KLb, VTb, mask, YHb);
    // output projection + bias: 512 blocks = 2/CU
    gemm_bf16<<<dim3(8, 64, 1), blk, 0, stream>>>(YHb, nullptr, WqH, WqL, WkH, WkL, WvH, WuH,
                                                  nullptr, nullptr, nullptr, nullptr, nullptr,
                                                  out, bu, 3);
}